// Round 1
// baseline (1417.360 us; speedup 1.0000x reference)
//
#include <hip/hip_runtime.h>
#include <hip/hip_bf16.h>

typedef float f32x4 __attribute__((ext_vector_type(4)));
typedef __bf16 bf16x8 __attribute__((ext_vector_type(8)));
typedef __bf16 bf16x4 __attribute__((ext_vector_type(4)));

// ---------------- model constants ----------------
#define NTOK 2048          // 2 batches x 1024 tokens
#define DM   1024
#define FF_DIM 4096
#define VOCAB 32000

// weight offsets (elements) in flat blocks array
#define W_EMBED 0ULL
#define W_L0    32768000ULL          // V*D
#define W_DD    1048576ULL           // D*D
#define W_FD    4194304ULL           // FF*D
#define W_LSTR  16777216ULL          // per-layer stride
#define W_LM    (W_L0 + 2ULL*W_LSTR)

// workspace offsets (bytes)
#define OFF_H      0ULL
#define OFF_HBF    8388608ULL
#define OFF_QBF    12582912ULL
#define OFF_KBF    16777216ULL
#define OFF_VTBF   20971520ULL
#define OFF_PBF    25165824ULL
#define OFF_ATTNBF 29360128ULL
#define OFF_FFBF   33554432ULL
#define OFF_BIG    50331648ULL       // qkv f32 (25.2MB) / g f32 (33.5MB) reuse
#define OFF_S      (OFF_BIG + 25165824ULL)   // S f32 (8.4MB), dead before g written

// ---------------- embed gather ----------------
__global__ __launch_bounds__(256) void embed_kernel(const int* __restrict__ ids,
    const float* __restrict__ blocks, float* __restrict__ h, __bf16* __restrict__ hbf)
{
    int t = blockIdx.x, tid = threadIdx.x;
    size_t row = (size_t)ids[t];
    float4 v = ((const float4*)(blocks + row * DM))[tid];
    ((float4*)(h + (size_t)t * DM))[tid] = v;
    bf16x4 b; b[0]=(__bf16)v.x; b[1]=(__bf16)v.y; b[2]=(__bf16)v.z; b[3]=(__bf16)v.w;
    ((bf16x4*)(hbf + (size_t)t * DM))[tid] = b;
}

// ---------------- RoPE: qkv f32 -> qbf/kbf bf16 ----------------
__global__ __launch_bounds__(256) void rope_kernel(const float* __restrict__ qkv,
    __bf16* __restrict__ qbf, __bf16* __restrict__ kbf)
{
    int t = blockIdx.x, tid = threadIdx.x;
    int s = t & 1023;
    const float* rowp = qkv + (size_t)t * 3072;
    #pragma unroll
    for (int jj = 0; jj < 2; ++jj) {
        int j = tid + jj * 256;                       // 0..511
        float freq = expf((float)j * -0.017988946039f); // -ln(10000)/512
        float ang = (float)s * freq;
        float sn, cs; sincosf(ang, &sn, &cs);
        float q1 = rowp[j], q2 = rowp[j + 512];
        qbf[(size_t)t * DM + j]       = (__bf16)(q1 * cs - q2 * sn);
        qbf[(size_t)t * DM + j + 512] = (__bf16)(q2 * cs + q1 * sn);
        float k1 = rowp[1024 + j], k2 = rowp[1024 + j + 512];
        kbf[(size_t)t * DM + j]       = (__bf16)(k1 * cs - k2 * sn);
        kbf[(size_t)t * DM + j + 512] = (__bf16)(k2 * cs + k1 * sn);
    }
}

// ---------------- V transpose: qkv cols 2048..3071 -> vt[b][d][s] bf16 ----------------
__global__ __launch_bounds__(1024) void vtrans_kernel(const float* __restrict__ qkv,
    __bf16* __restrict__ vt)
{
    __shared__ float tile[32][33];
    int b = blockIdx.z;
    int s0 = blockIdx.x * 32, d0 = blockIdx.y * 32;
    int tx = threadIdx.x, ty = threadIdx.y;
    tile[ty][tx] = qkv[(size_t)(b * 1024 + s0 + ty) * 3072 + 2048 + d0 + tx];
    __syncthreads();
    vt[(size_t)b * 1048576 + (size_t)(d0 + ty) * 1024 + (s0 + tx)] = (__bf16)tile[tx][ty];
}

// ---------------- row softmax (scale folded), f32 -> bf16 ----------------
__global__ __launch_bounds__(256) void softmax_kernel(const float* __restrict__ S,
    __bf16* __restrict__ P)
{
    __shared__ float red[8];
    int row = blockIdx.x, tid = threadIdx.x, lane = tid & 63, wave = tid >> 6;
    const float* sr = S + (size_t)row * 1024;
    float4 v = ((const float4*)sr)[tid];
    const float sc = 0.03125f;   // 1/sqrt(1024)
    float a0 = v.x * sc, a1 = v.y * sc, a2 = v.z * sc, a3 = v.w * sc;
    float m = fmaxf(fmaxf(a0, a1), fmaxf(a2, a3));
    #pragma unroll
    for (int o = 32; o > 0; o >>= 1) m = fmaxf(m, __shfl_xor(m, o));
    if (lane == 0) red[wave] = m;
    __syncthreads();
    m = fmaxf(fmaxf(red[0], red[1]), fmaxf(red[2], red[3]));
    float e0 = expf(a0 - m), e1 = expf(a1 - m), e2 = expf(a2 - m), e3 = expf(a3 - m);
    float sum = e0 + e1 + e2 + e3;
    #pragma unroll
    for (int o = 32; o > 0; o >>= 1) sum += __shfl_xor(sum, o);
    if (lane == 0) red[4 + wave] = sum;
    __syncthreads();
    float inv = 1.f / (red[4] + red[5] + red[6] + red[7]);
    bf16x4 pb;
    pb[0] = (__bf16)(e0 * inv); pb[1] = (__bf16)(e1 * inv);
    pb[2] = (__bf16)(e2 * inv); pb[3] = (__bf16)(e3 * inv);
    ((bf16x4*)(P + (size_t)row * 1024))[tid] = pb;
}

// ---------------- GEMM: C[m][n] = sum_k A[m][k] * B[n][k]  (NT) ----------------
enum { EPI_F32 = 0, EPI_BF16 = 1, EPI_RES = 2, EPI_SWIGLU = 3 };

__device__ __forceinline__ bf16x8 ld8(const __bf16* p) { return *(const bf16x8*)p; }
__device__ __forceinline__ bf16x8 ld8(const float* p) {
    float4 x = *(const float4*)p, y = *(const float4*)(p + 4);
    bf16x8 r;
    r[0]=(__bf16)x.x; r[1]=(__bf16)x.y; r[2]=(__bf16)x.z; r[3]=(__bf16)x.w;
    r[4]=(__bf16)y.x; r[5]=(__bf16)y.y; r[6]=(__bf16)y.z; r[7]=(__bf16)y.w;
    return r;
}

template<typename TA, typename TB, int EPI>
__global__ __launch_bounds__(256) void gemm_nt(
    const TA* __restrict__ A, int lda, long sA,
    const TB* __restrict__ B, int ldb, long sB,
    float* __restrict__ C, int ldc, long sC,
    __bf16* __restrict__ Obf, long sO,
    const float* __restrict__ aux, long sAux,
    int K)
{
    __shared__ __bf16 As[128][72];   // pad 64->72: stride 144B, 2-way-free banks
    __shared__ __bf16 Bs[128][72];
    const int tid = threadIdx.x, lane = tid & 63, wave = tid >> 6;
    const int wr = wave >> 1, wc = wave & 1;
    const int bm = blockIdx.y * 128, bn = blockIdx.x * 128, b = blockIdx.z;

    const TA* Ap = A + (size_t)b * sA + (size_t)bm * lda;
    const TB* Bp = B + (size_t)b * sB + (size_t)bn * ldb;

    f32x4 acc[4][4];
    #pragma unroll
    for (int i = 0; i < 4; ++i)
        #pragma unroll
        for (int j = 0; j < 4; ++j)
            acc[i][j] = (f32x4){0.f, 0.f, 0.f, 0.f};

    const int srow = tid >> 3, sseg = tid & 7;

    for (int kt = 0; kt < K; kt += 64) {
        #pragma unroll
        for (int i = 0; i < 4; ++i) {
            int r = srow + 32 * i;
            *(bf16x8*)&As[r][sseg * 8] = ld8(Ap + (size_t)r * lda + kt + sseg * 8);
            *(bf16x8*)&Bs[r][sseg * 8] = ld8(Bp + (size_t)r * ldb + kt + sseg * 8);
        }
        __syncthreads();
        #pragma unroll
        for (int kk = 0; kk < 64; kk += 32) {
            bf16x8 af[4], bfr[4];
            #pragma unroll
            for (int f = 0; f < 4; ++f) {
                af[f]  = *(const bf16x8*)&As[wr * 64 + f * 16 + (lane & 15)][kk + (lane >> 4) * 8];
                bfr[f] = *(const bf16x8*)&Bs[wc * 64 + f * 16 + (lane & 15)][kk + (lane >> 4) * 8];
            }
            #pragma unroll
            for (int fm = 0; fm < 4; ++fm)
                #pragma unroll
                for (int fn = 0; fn < 4; ++fn)
                    acc[fm][fn] = __builtin_amdgcn_mfma_f32_16x16x32_bf16(
                        af[fm], bfr[fn], acc[fm][fn], 0, 0, 0);
        }
        __syncthreads();
    }

    // epilogue: C/D mapping col=lane&15, row=(lane>>4)*4+r  [m89-verified]
    const int rowb = bm + wr * 64 + (lane >> 4) * 4;
    const int colb = bn + wc * 64 + (lane & 15);
    #pragma unroll
    for (int fm = 0; fm < 4; ++fm) {
        #pragma unroll
        for (int fn = 0; fn < 4; ++fn) {
            int rr = rowb + fm * 16, cc = colb + fn * 16;
            #pragma unroll
            for (int r = 0; r < 4; ++r) {
                size_t idx = (size_t)(rr + r) * ldc + cc;
                float v = acc[fm][fn][r];
                if constexpr (EPI == EPI_F32) {
                    (C + (size_t)b * sC)[idx] = v;
                } else if constexpr (EPI == EPI_BF16) {
                    (Obf + (size_t)b * sO)[idx] = (__bf16)v;
                } else if constexpr (EPI == EPI_RES) {
                    float o = v + (aux + (size_t)b * sAux)[idx];
                    (C + (size_t)b * sC)[idx] = o;
                    (Obf + (size_t)b * sO)[idx] = (__bf16)o;
                } else { // EPI_SWIGLU: out = up * silu(gate)
                    float g = (aux + (size_t)b * sAux)[idx];
                    float s = g / (1.f + expf(-g));
                    (Obf + (size_t)b * sO)[idx] = (__bf16)(v * s);
                }
            }
        }
    }
}

// ---------------- host ----------------
extern "C" void kernel_launch(void* const* d_in, const int* in_sizes, int n_in,
                              void* d_out, int out_size, void* d_ws, size_t ws_size,
                              hipStream_t stream)
{
    const int*   ids    = (const int*)d_in[0];
    const float* blocks = (const float*)d_in[1];
    float*       out    = (float*)d_out;
    char*        ws     = (char*)d_ws;

    float*  h      = (float*)(ws + OFF_H);
    __bf16* hbf    = (__bf16*)(ws + OFF_HBF);
    __bf16* qbf    = (__bf16*)(ws + OFF_QBF);
    __bf16* kbf    = (__bf16*)(ws + OFF_KBF);
    __bf16* vtbf   = (__bf16*)(ws + OFF_VTBF);
    __bf16* pbf    = (__bf16*)(ws + OFF_PBF);
    __bf16* attnbf = (__bf16*)(ws + OFF_ATTNBF);
    __bf16* ffbf   = (__bf16*)(ws + OFF_FFBF);
    float*  qkv    = (float*)(ws + OFF_BIG);
    float*  gbuf   = (float*)(ws + OFF_BIG);
    float*  Sbuf   = (float*)(ws + OFF_S);

    dim3 blk(256);

    embed_kernel<<<NTOK, blk, 0, stream>>>(ids, blocks, h, hbf);

    for (int i = 0; i < 2; ++i) {
        const float* wq = blocks + W_L0 + (size_t)i * W_LSTR;
        const float* wo = wq + 3 * W_DD;
        const float* wg = wq + 4 * W_DD;
        const float* wu = wg + W_FD;
        const float* wd = wu + W_FD;

        // fused QKV GEMM: (2048x1024) x (3072x1024)^T -> qkv f32
        gemm_nt<__bf16, float, EPI_F32><<<dim3(24, 16, 1), blk, 0, stream>>>(
            hbf, DM, 0, wq, DM, 0, qkv, 3072, 0, ((__bf16*)0), 0, ((const float*)0), 0, DM);

        rope_kernel<<<NTOK, blk, 0, stream>>>(qkv, qbf, kbf);
        vtrans_kernel<<<dim3(32, 32, 2), dim3(32, 32), 0, stream>>>(qkv, vtbf);

        // S = Q K^T per batch
        gemm_nt<__bf16, __bf16, EPI_F32><<<dim3(8, 8, 2), blk, 0, stream>>>(
            qbf, DM, 1048576, kbf, DM, 1048576, Sbuf, 1024, 1048576,
            ((__bf16*)0), 0, ((const float*)0), 0, DM);

        softmax_kernel<<<NTOK, blk, 0, stream>>>(Sbuf, pbf);

        // attn = P @ V  (V stored transposed) -> bf16
        gemm_nt<__bf16, __bf16, EPI_BF16><<<dim3(8, 8, 2), blk, 0, stream>>>(
            pbf, 1024, 1048576, vtbf, 1024, 1048576, ((float*)0), 1024, 0,
            attnbf, 1048576, ((const float*)0), 0, DM);

        // O-proj + residual -> h (f32) and hbf
        gemm_nt<__bf16, float, EPI_RES><<<dim3(8, 16, 1), blk, 0, stream>>>(
            attnbf, DM, 0, wo, DM, 0, h, DM, 0, hbf, 0, h, 0, DM);

        // gate GEMM -> gbuf f32
        gemm_nt<__bf16, float, EPI_F32><<<dim3(32, 16, 1), blk, 0, stream>>>(
            hbf, DM, 0, wg, DM, 0, gbuf, FF_DIM, 0, ((__bf16*)0), 0, ((const float*)0), 0, DM);

        // up GEMM + swiglu -> ffbf bf16
        gemm_nt<__bf16, float, EPI_SWIGLU><<<dim3(32, 16, 1), blk, 0, stream>>>(
            hbf, DM, 0, wu, DM, 0, ((float*)0), FF_DIM, 0, ffbf, 0, gbuf, 0, DM);

        // down GEMM + residual -> h, hbf
        gemm_nt<__bf16, float, EPI_RES><<<dim3(8, 16, 1), blk, 0, stream>>>(
            ffbf, FF_DIM, 0, wd, FF_DIM, 0, h, DM, 0, hbf, 0, h, 0, FF_DIM);
    }

    // LM head: (2048x1024) x (32000x1024)^T -> out f32
    gemm_nt<__bf16, float, EPI_F32><<<dim3(250, 16, 1), blk, 0, stream>>>(
        hbf, DM, 0, blocks + W_LM, DM, 0, out, VOCAB, 0,
        ((__bf16*)0), 0, ((const float*)0), 0, DM);
}